// Round 2
// baseline (1775.899 us; speedup 1.0000x reference)
//
#include <hip/hip_runtime.h>

typedef __bf16 bf16x8 __attribute__((ext_vector_type(8)));
typedef float  f32x4  __attribute__((ext_vector_type(4)));

__device__ __forceinline__ float b2f(ushort u){
  return __builtin_bit_cast(float, ((uint)u) << 16);
}
__device__ __forceinline__ ushort f2b(float f){
  uint i = __builtin_bit_cast(uint, f);
  uint r = i + 0x7FFFu + ((i >> 16) & 1u);
  return (ushort)(r >> 16);
}
// convert 8 consecutive floats -> 8 packed bf16 (uint4)
__device__ __forceinline__ uint4 cvt8(const float* __restrict__ p){
  float4 a = *reinterpret_cast<const float4*>(p);
  float4 b = *reinterpret_cast<const float4*>(p + 4);
  uint4 r;
  r.x = (uint)f2b(a.x) | ((uint)f2b(a.y) << 16);
  r.y = (uint)f2b(a.z) | ((uint)f2b(a.w) << 16);
  r.z = (uint)f2b(b.x) | ((uint)f2b(b.y) << 16);
  r.w = (uint)f2b(b.z) | ((uint)f2b(b.w) << 16);
  return r;
}

// ---------------------------------------------------------------------------
// Tiled MFMA GEMM: C[M][N] = A[M][K] * B[N][K]^T
// A: fp32 (AF32=true) or bf16 ws buffer; B: always fp32 (weights), converted
// to bf16 during LDS staging. 128x128 tile, BK=32, 4 waves (2x2), each wave
// 64x64 via 4x4 accs of 16x16x32 bf16 MFMA.
// EPI: 0 = split even/odd cols into out0/out1 (xz split, bf16)
//      1 = plain bf16 store (N-guarded)
//      2 = softplus(v + bias[n]) bf16 store
//      3 = plain fp32 store (final output)
// ---------------------------------------------------------------------------
#define BM 128
#define BN 128
#define BK 32

template<int EPI, bool AF32>
__global__ __launch_bounds__(256)
void gemm_kernel(const void* __restrict__ A, int lda,
                 const float* __restrict__ B, int ldb,
                 int M, int N, int K,
                 ushort* __restrict__ out0, ushort* __restrict__ out1,
                 float* __restrict__ outF, int ldo,
                 const float* __restrict__ bias)
{
  __shared__ ushort As[BM * BK];
  __shared__ ushort Bs[BN * BK];

  const int tid   = threadIdx.x;
  const int wave  = tid >> 6;
  const int lane  = tid & 63;
  const int row16 = lane & 15;
  const int quad  = lane >> 4;
  const int wm    = (wave >> 1) * 64;
  const int wn    = (wave & 1) * 64;
  const int tileM = blockIdx.y * BM;
  const int tileN = blockIdx.x * BN;

  f32x4 acc[4][4];
#pragma unroll
  for (int i = 0; i < 4; i++)
#pragma unroll
    for (int j = 0; j < 4; j++)
      acc[i][j] = f32x4{0.f, 0.f, 0.f, 0.f};

  for (int k0 = 0; k0 < K; k0 += BK) {
    // stage A/B tiles: each thread converts/copies 8 elements x 2 chunks
#pragma unroll
    for (int i = 0; i < 2; i++) {
      const int c   = tid + i * 256;
      const int row = c >> 2;
      const int seg = c & 3;
      uint4 av;
      if (AF32) {
        av = cvt8((const float*)A + (size_t)(tileM + row) * lda + k0 + seg * 8);
      } else {
        av = *reinterpret_cast<const uint4*>((const ushort*)A + (size_t)(tileM + row) * lda + k0 + seg * 8);
      }
      *reinterpret_cast<uint4*>(&As[row * BK + seg * 8]) = av;

      uint4 bv = uint4{0u, 0u, 0u, 0u};
      if (tileN + row < N)
        bv = cvt8(B + (size_t)(tileN + row) * ldb + k0 + seg * 8);
      *reinterpret_cast<uint4*>(&Bs[row * BK + seg * 8]) = bv;
    }
    __syncthreads();

    bf16x8 af[4], bfr[4];
#pragma unroll
    for (int mi = 0; mi < 4; mi++)
      af[mi] = *reinterpret_cast<const bf16x8*>(&As[(wm + mi * 16 + row16) * BK + quad * 8]);
#pragma unroll
    for (int ni = 0; ni < 4; ni++)
      bfr[ni] = *reinterpret_cast<const bf16x8*>(&Bs[(wn + ni * 16 + row16) * BK + quad * 8]);

#pragma unroll
    for (int mi = 0; mi < 4; mi++)
#pragma unroll
      for (int ni = 0; ni < 4; ni++)
        acc[mi][ni] = __builtin_amdgcn_mfma_f32_16x16x32_bf16(af[mi], bfr[ni], acc[mi][ni], 0, 0, 0);
    __syncthreads();
  }

  // epilogue: C row = quad*4 + reg, col = lane&15  (verified gfx950 layout)
#pragma unroll
  for (int mi = 0; mi < 4; mi++) {
#pragma unroll
    for (int ni = 0; ni < 4; ni++) {
      const int nbase = tileN + wn + ni * 16 + row16;
#pragma unroll
      for (int r = 0; r < 4; r++) {
        const int m = tileM + wm + mi * 16 + quad * 4 + r;
        float v = acc[mi][ni][r];
        if (EPI == 0) {
          const ushort hv = f2b(v);
          const size_t idx = (size_t)m * ldo + (nbase >> 1);
          if (nbase & 1) out1[idx] = hv; else out0[idx] = hv;
        } else if (EPI == 1) {
          if (nbase < N) out0[(size_t)m * ldo + nbase] = f2b(v);
        } else if (EPI == 2) {
          float t = v + bias[nbase];
          float sp = (t > 20.0f) ? t : __logf(1.0f + __expf(t));
          out0[(size_t)m * ldo + nbase] = f2b(sp);
        } else {
          if (nbase < N) outF[(size_t)m * ldo + nbase] = v;
        }
      }
    }
  }
}

// ---------------------------------------------------------------------------
// Depthwise causal conv (width 4) + bias + SiLU.  x (bf16 ws) in [b][l][d].
// conv_w/conv_b fp32. Thread handles 8 consecutive d for one (b,l).
// ---------------------------------------------------------------------------
__global__ __launch_bounds__(256)
void conv_silu_kernel(const ushort* __restrict__ xraw, const float* __restrict__ cw,
                      const float* __restrict__ cb, ushort* __restrict__ xact)
{
  const int t  = blockIdx.x * 256 + threadIdx.x;   // [0, 4096*512)
  const int m  = t >> 9;
  const int d0 = (t & 511) << 3;
  const int l  = m & 2047;

  float acc[8];
  {
    float4 c0 = *reinterpret_cast<const float4*>(cb + d0);
    float4 c1 = *reinterpret_cast<const float4*>(cb + d0 + 4);
    acc[0] = c0.x; acc[1] = c0.y; acc[2] = c0.z; acc[3] = c0.w;
    acc[4] = c1.x; acc[5] = c1.y; acc[6] = c1.z; acc[7] = c1.w;
  }
  float wf[8][4];
#pragma unroll
  for (int i = 0; i < 8; i++) {
    float4 w4 = *reinterpret_cast<const float4*>(cw + (size_t)(d0 + i) * 4);
    wf[i][0] = w4.x; wf[i][1] = w4.y; wf[i][2] = w4.z; wf[i][3] = w4.w;
  }
#pragma unroll
  for (int k = 0; k < 4; k++) {
    const int lsrc = l - 3 + k;
    if (lsrc >= 0) {
      uint4 xv = *reinterpret_cast<const uint4*>(xraw + (size_t)(m - 3 + k) * 4096 + d0);
      const ushort* xp = (const ushort*)&xv;
#pragma unroll
      for (int i = 0; i < 8; i++) acc[i] += b2f(xp[i]) * wf[i][k];
    }
  }
  uint4 ov;
  ushort* op = (ushort*)&ov;
#pragma unroll
  for (int i = 0; i < 8; i++) {
    float a = acc[i];
    float s = a / (1.0f + __expf(-a));
    op[i] = f2b(s);
  }
  *reinterpret_cast<uint4*>(xact + (size_t)m * 4096 + d0) = ov;
}

// ---------------------------------------------------------------------------
// Selective scan. Thread = (b, d, nq) with 4 states (n = nq*4..nq*4+3).
// Block = 256 threads = 64 d's, grid (64, B). Chunked LDS staging of
// dt/x/z (per-d, bf16 ws) and B/C (shared, bf16 ws), 64 l-steps per chunk.
// A_log / D are fp32 inputs. y = (sum_n state*C + D*x) * silu(z) -> bf16 ws.
// ---------------------------------------------------------------------------
#define SCHUNK 64
__global__ __launch_bounds__(256)
void scan_kernel(const ushort* __restrict__ dtb,   // [B*L][4096] bf16
                 const ushort* __restrict__ xact,  // [B*L][4096] bf16
                 const ushort* __restrict__ zb,    // [B*L][4096] bf16
                 const ushort* __restrict__ xdbl,  // [B*L][160]  bf16
                 const float*  __restrict__ Alog,  // [4096][16]  fp32
                 const float*  __restrict__ Dp,    // [4096]      fp32
                 ushort* __restrict__ y)           // [B*L][4096] bf16
{
  __shared__ ushort sdt[SCHUNK][64];
  __shared__ ushort sx [SCHUNK][64];
  __shared__ ushort sz [SCHUNK][64];
  __shared__ ushort sbc[SCHUNK][32];
  __shared__ ushort sy [SCHUNK][64];

  const int tid  = threadIdx.x;
  const int b    = blockIdx.y;
  const int dblk = blockIdx.x * 64;
  const int dd   = tid >> 2;
  const int nq   = tid & 3;
  const int d    = dblk + dd;

  float a2[4];
#pragma unroll
  for (int n = 0; n < 4; n++)
    a2[n] = -__expf(Alog[(size_t)d * 16 + nq * 4 + n]) * 1.44269504f;
  const float Dd = Dp[d];
  float st[4] = {0.f, 0.f, 0.f, 0.f};

  const size_t base = (size_t)b * 2048;
  for (int l0 = 0; l0 < 2048; l0 += SCHUNK) {
    // stage dt/x/z: 64 rows x 64 cols bf16 each -> 2 x 16B per thread
#pragma unroll
    for (int i = 0; i < 2; i++) {
      const int c = tid + i * 256;
      const int r = c >> 3, s = c & 7;
      const size_t g = (base + l0 + r) * 4096 + dblk + s * 8;
      *reinterpret_cast<uint4*>(&sdt[r][s * 8]) = *reinterpret_cast<const uint4*>(dtb + g);
      *reinterpret_cast<uint4*>(&sx [r][s * 8]) = *reinterpret_cast<const uint4*>(xact + g);
      *reinterpret_cast<uint4*>(&sz [r][s * 8]) = *reinterpret_cast<const uint4*>(zb + g);
    }
    { // stage B/C: 64 rows x 32 bf16 -> one 16B per thread
      const int r = tid >> 2, s = tid & 3;
      *reinterpret_cast<uint4*>(&sbc[r][s * 8]) =
          *reinterpret_cast<const uint4*>(xdbl + (base + l0 + r) * 160 + 128 + s * 8);
    }
    __syncthreads();

    for (int l = 0; l < SCHUNK; l++) {
      const float dtv = b2f(sdt[l][dd]);
      const float xv  = b2f(sx[l][dd]);
      const float u   = dtv * xv;
      ushort4 Bv = *reinterpret_cast<const ushort4*>(&sbc[l][nq * 4]);
      ushort4 Cv = *reinterpret_cast<const ushort4*>(&sbc[l][16 + nq * 4]);
      const ushort* Bp = (const ushort*)&Bv;
      const ushort* Cp = (const ushort*)&Cv;
      float p = 0.f;
#pragma unroll
      for (int n = 0; n < 4; n++) {
        const float dA = exp2f(dtv * a2[n]);
        st[n] = fmaf(st[n], dA, u * b2f(Bp[n]));
        p = fmaf(st[n], b2f(Cp[n]), p);
      }
      p += __shfl_xor(p, 1);
      p += __shfl_xor(p, 2);
      if (nq == 0) {
        const float zv = b2f(sz[l][dd]);
        const float sig = 1.0f / (1.0f + __expf(-zv));
        const float yv = (p + Dd * xv) * (zv * sig);
        sy[l][dd] = f2b(yv);
      }
    }
    __syncthreads();

    // writeout y chunk (coalesced)
#pragma unroll
    for (int i = 0; i < 2; i++) {
      const int c = tid + i * 256;
      const int r = c >> 3, s = c & 7;
      *reinterpret_cast<uint4*>(y + (base + l0 + r) * 4096 + dblk + s * 8) =
          *reinterpret_cast<const uint4*>(&sy[r][s * 8]);
    }
    __syncthreads();
  }
}

// ---------------------------------------------------------------------------
extern "C" void kernel_launch(void* const* d_in, const int* in_sizes, int n_in,
                              void* d_out, int out_size, void* d_ws, size_t ws_size,
                              hipStream_t stream)
{
  const float* hid  = (const float*)d_in[0];  // (2,2048,2048) fp32
  const float* Win  = (const float*)d_in[1];  // (8192,2048)   fp32
  const float* cw   = (const float*)d_in[2];  // (4096,4)      fp32
  const float* cb   = (const float*)d_in[3];  // (4096,)       fp32
  const float* Wx   = (const float*)d_in[4];  // (160,4096)    fp32
  const float* Wdt  = (const float*)d_in[5];  // (4096,128)    fp32
  const float* bdt  = (const float*)d_in[6];  // (4096,)       fp32
  const float* Alog = (const float*)d_in[7];  // (4096,16)     fp32
  const float* Dp   = (const float*)d_in[8];  // (4096,)       fp32
  const float* Wout = (const float*)d_in[9];  // (2048,4096)   fp32
  float* outp = (float*)d_out;                // (2,2048,2048) fp32

  char* ws = (char*)d_ws;
  const size_t SZ = (size_t)4096 * 4096 * sizeof(ushort);  // 33.5 MB per [B*L][D_INNER] bf16
  ushort* buf0 = (ushort*)(ws);            // x_raw, later dt
  ushort* buf1 = (ushort*)(ws + SZ);       // z, later y
  ushort* buf2 = (ushort*)(ws + 2 * SZ);   // x_act
  ushort* buf3 = (ushort*)(ws + 3 * SZ);   // x_dbl [4096][160]

  // 1) xz = hidden @ W_in^T, split into x (even e) / z (odd e), [b][l][d]
  gemm_kernel<0, true><<<dim3(8192 / BN, 4096 / BM), 256, 0, stream>>>(
      hid, 2048, Win, 2048, 4096, 8192, 2048, buf0, buf1, nullptr, 4096, nullptr);

  // 2) causal depthwise conv + SiLU
  conv_silu_kernel<<<(4096 * 512) / 256, 256, 0, stream>>>(buf0, cw, cb, buf2);

  // 3) x_dbl = x_act @ W_x^T  [4096][160]
  gemm_kernel<1, false><<<dim3(2, 4096 / BM), 256, 0, stream>>>(
      buf2, 4096, Wx, 4096, 4096, 160, 4096, buf3, nullptr, nullptr, 160, nullptr);

  // 4) dt = softplus(dt_lr @ W_dt^T + b_dt)  [4096][4096] (into buf0)
  gemm_kernel<2, false><<<dim3(4096 / BN, 4096 / BM), 256, 0, stream>>>(
      buf3, 160, Wdt, 128, 4096, 4096, 128, buf0, nullptr, nullptr, 4096, bdt);

  // 5) selective scan -> y (into buf1, overwriting z chunk-safely)
  scan_kernel<<<dim3(64, 2), 256, 0, stream>>>(buf0, buf2, buf1, buf3, Alog, Dp, buf1);

  // 6) out = y @ W_out^T -> fp32 d_out
  gemm_kernel<3, false><<<dim3(2048 / BN, 4096 / BM), 256, 0, stream>>>(
      buf1, 4096, Wout, 4096, 4096, 2048, 4096, nullptr, nullptr, outp, 2048, nullptr);
}

// Round 3
// 1200.109 us; speedup vs baseline: 1.4798x; 1.4798x over previous
//
#include <hip/hip_runtime.h>

typedef __bf16 bf16x8 __attribute__((ext_vector_type(8)));
typedef float  f32x4  __attribute__((ext_vector_type(4)));

__device__ __forceinline__ float b2f(ushort u){
  return __builtin_bit_cast(float, ((uint)u) << 16);
}
__device__ __forceinline__ ushort f2b(float f){
  uint i = __builtin_bit_cast(uint, f);
  uint r = i + 0x7FFFu + ((i >> 16) & 1u);
  return (ushort)(r >> 16);
}
// convert 8 consecutive floats -> 8 packed bf16 (uint4)
__device__ __forceinline__ uint4 cvt8(const float* __restrict__ p){
  float4 a = *reinterpret_cast<const float4*>(p);
  float4 b = *reinterpret_cast<const float4*>(p + 4);
  uint4 r;
  r.x = (uint)f2b(a.x) | ((uint)f2b(a.y) << 16);
  r.y = (uint)f2b(a.z) | ((uint)f2b(a.w) << 16);
  r.z = (uint)f2b(b.x) | ((uint)f2b(b.y) << 16);
  r.w = (uint)f2b(b.z) | ((uint)f2b(b.w) << 16);
  return r;
}

// ---------------------------------------------------------------------------
// Tiled MFMA GEMM: C[M][N] = A[M][K] * B[N][K]^T
// A: fp32 (AF32) or bf16 ws; B: fp32 weights, converted during LDS staging.
// 128x128 tile, BK=32, 4 waves (2x2), each wave 64x64 (4x4 x 16x16x32 MFMA).
// kSlice: K-range per blockIdx.z (split-K support; pass K for no split).
// EPI: 0 xz-split bf16, 1 bf16 (N-guard), 2 softplus+bias bf16,
//      3 fp32 store, 4 fp32 atomicAdd (split-K partials)
// ---------------------------------------------------------------------------
#define BM 128
#define BN 128
#define BK 32

template<int EPI, bool AF32>
__global__ __launch_bounds__(256)
void gemm_kernel(const void* __restrict__ A, int lda,
                 const float* __restrict__ B, int ldb,
                 int M, int N, int K, int kSlice,
                 ushort* __restrict__ out0, ushort* __restrict__ out1,
                 float* __restrict__ outF, int ldo,
                 const float* __restrict__ bias)
{
  __shared__ ushort As[BM * BK];
  __shared__ ushort Bs[BN * BK];

  const int tid   = threadIdx.x;
  const int wave  = tid >> 6;
  const int lane  = tid & 63;
  const int row16 = lane & 15;
  const int quad  = lane >> 4;
  const int wm    = (wave >> 1) * 64;
  const int wn    = (wave & 1) * 64;
  const int tileM = blockIdx.y * BM;
  const int tileN = blockIdx.x * BN;
  const int kBeg  = blockIdx.z * kSlice;

  f32x4 acc[4][4];
#pragma unroll
  for (int i = 0; i < 4; i++)
#pragma unroll
    for (int j = 0; j < 4; j++)
      acc[i][j] = f32x4{0.f, 0.f, 0.f, 0.f};

  for (int k0 = kBeg; k0 < kBeg + kSlice; k0 += BK) {
#pragma unroll
    for (int i = 0; i < 2; i++) {
      const int c   = tid + i * 256;
      const int row = c >> 2;
      const int seg = c & 3;
      uint4 av;
      if (AF32) {
        av = cvt8((const float*)A + (size_t)(tileM + row) * lda + k0 + seg * 8);
      } else {
        av = *reinterpret_cast<const uint4*>((const ushort*)A + (size_t)(tileM + row) * lda + k0 + seg * 8);
      }
      *reinterpret_cast<uint4*>(&As[row * BK + seg * 8]) = av;

      uint4 bv = uint4{0u, 0u, 0u, 0u};
      if (tileN + row < N)
        bv = cvt8(B + (size_t)(tileN + row) * ldb + k0 + seg * 8);
      *reinterpret_cast<uint4*>(&Bs[row * BK + seg * 8]) = bv;
    }
    __syncthreads();

    bf16x8 af[4], bfr[4];
#pragma unroll
    for (int mi = 0; mi < 4; mi++)
      af[mi] = *reinterpret_cast<const bf16x8*>(&As[(wm + mi * 16 + row16) * BK + quad * 8]);
#pragma unroll
    for (int ni = 0; ni < 4; ni++)
      bfr[ni] = *reinterpret_cast<const bf16x8*>(&Bs[(wn + ni * 16 + row16) * BK + quad * 8]);

#pragma unroll
    for (int mi = 0; mi < 4; mi++)
#pragma unroll
      for (int ni = 0; ni < 4; ni++)
        acc[mi][ni] = __builtin_amdgcn_mfma_f32_16x16x32_bf16(af[mi], bfr[ni], acc[mi][ni], 0, 0, 0);
    __syncthreads();
  }

  // epilogue: C row = quad*4 + reg, col = lane&15
#pragma unroll
  for (int mi = 0; mi < 4; mi++) {
#pragma unroll
    for (int ni = 0; ni < 4; ni++) {
      const int nbase = tileN + wn + ni * 16 + row16;
#pragma unroll
      for (int r = 0; r < 4; r++) {
        const int m = tileM + wm + mi * 16 + quad * 4 + r;
        float v = acc[mi][ni][r];
        if (EPI == 0) {
          const ushort hv = f2b(v);
          const size_t idx = (size_t)m * ldo + (nbase >> 1);
          if (nbase & 1) out1[idx] = hv; else out0[idx] = hv;
        } else if (EPI == 1) {
          if (nbase < N) out0[(size_t)m * ldo + nbase] = f2b(v);
        } else if (EPI == 2) {
          float t = v + bias[nbase];
          float sp = (t > 20.0f) ? t : __logf(1.0f + __expf(t));
          out0[(size_t)m * ldo + nbase] = f2b(sp);
        } else if (EPI == 3) {
          if (nbase < N) outF[(size_t)m * ldo + nbase] = v;
        } else {
          if (nbase < N) atomicAdd(&outF[(size_t)m * ldo + nbase], v);
        }
      }
    }
  }
}

// ---------------------------------------------------------------------------
// fp32 -> bf16 convert (vectorized x4)
// ---------------------------------------------------------------------------
__global__ __launch_bounds__(256)
void f32_to_bf16_kernel(const float* __restrict__ in, ushort* __restrict__ out, int n4)
{
  const int t = blockIdx.x * 256 + threadIdx.x;
  if (t < n4) {
    float4 v = *reinterpret_cast<const float4*>(in + (size_t)t * 4);
    ushort4 o;
    o.x = f2b(v.x); o.y = f2b(v.y); o.z = f2b(v.z); o.w = f2b(v.w);
    *reinterpret_cast<ushort4*>(out + (size_t)t * 4) = o;
  }
}

// ---------------------------------------------------------------------------
// Depthwise causal conv (width 4) + bias + SiLU.  x (bf16 ws) in [b][l][d].
// ---------------------------------------------------------------------------
__global__ __launch_bounds__(256)
void conv_silu_kernel(const ushort* __restrict__ xraw, const float* __restrict__ cw,
                      const float* __restrict__ cb, ushort* __restrict__ xact)
{
  const int t  = blockIdx.x * 256 + threadIdx.x;
  const int m  = t >> 9;
  const int d0 = (t & 511) << 3;
  const int l  = m & 2047;

  float acc[8];
  {
    float4 c0 = *reinterpret_cast<const float4*>(cb + d0);
    float4 c1 = *reinterpret_cast<const float4*>(cb + d0 + 4);
    acc[0] = c0.x; acc[1] = c0.y; acc[2] = c0.z; acc[3] = c0.w;
    acc[4] = c1.x; acc[5] = c1.y; acc[6] = c1.z; acc[7] = c1.w;
  }
  float wf[8][4];
#pragma unroll
  for (int i = 0; i < 8; i++) {
    float4 w4 = *reinterpret_cast<const float4*>(cw + (size_t)(d0 + i) * 4);
    wf[i][0] = w4.x; wf[i][1] = w4.y; wf[i][2] = w4.z; wf[i][3] = w4.w;
  }
#pragma unroll
  for (int k = 0; k < 4; k++) {
    const int lsrc = l - 3 + k;
    if (lsrc >= 0) {
      uint4 xv = *reinterpret_cast<const uint4*>(xraw + (size_t)(m - 3 + k) * 4096 + d0);
      const ushort* xp = (const ushort*)&xv;
#pragma unroll
      for (int i = 0; i < 8; i++) acc[i] += b2f(xp[i]) * wf[i][k];
    }
  }
  uint4 ov;
  ushort* op = (ushort*)&ov;
#pragma unroll
  for (int i = 0; i < 8; i++) {
    float a = acc[i];
    float s = a / (1.0f + __expf(-a));
    op[i] = f2b(s);
  }
  *reinterpret_cast<uint4*>(xact + (size_t)m * 4096 + d0) = ov;
}

// ---------------------------------------------------------------------------
// Chunked parallel scan.  L=2048 -> NC=16 chunks of CLEN=128.
// Phase A: per-chunk local scan (zero init). Thread=(b,d,nq), block=64 d x 4 nq,
// grid (64 dblk, B, NC). Writes partA = y_loc + D*x IN-PLACE over xact, and
// per-chunk final state S / cumprod P (fp32, in d_out scratch).
// ---------------------------------------------------------------------------
#define NC 16
#define CLEN 128
#define SCH 64

__global__ __launch_bounds__(256)
void scan_partA(const ushort* __restrict__ dtb,
                ushort* __restrict__ xact,          // in: x_act, out: partA
                const ushort* __restrict__ xdbl,
                const float*  __restrict__ Alog,
                const float*  __restrict__ Dp,
                float* __restrict__ Sout, float* __restrict__ Pout)
{
  __shared__ ushort sdt[SCH][64];
  __shared__ ushort sx [SCH][64];
  __shared__ ushort sbc[SCH][32];

  const int tid  = threadIdx.x;
  const int dblk = blockIdx.x * 64;
  const int b    = blockIdx.y;
  const int c    = blockIdx.z;
  const int dd   = tid >> 2;
  const int nq   = tid & 3;
  const int d    = dblk + dd;

  float a2[4];
#pragma unroll
  for (int n = 0; n < 4; n++)
    a2[n] = -__expf(Alog[(size_t)d * 16 + nq * 4 + n]) * 1.44269504f;
  const float Dd = Dp[d];

  float st[4] = {0.f, 0.f, 0.f, 0.f};
  float q [4] = {1.f, 1.f, 1.f, 1.f};

  const size_t rbase = (size_t)b * 2048 + (size_t)c * CLEN;
  for (int sub = 0; sub < CLEN / SCH; sub++) {
    const size_t l0 = rbase + sub * SCH;
#pragma unroll
    for (int i = 0; i < 2; i++) {
      const int cc = tid + i * 256;
      const int r = cc >> 3, s = cc & 7;
      const size_t g = (l0 + r) * 4096 + dblk + s * 8;
      *reinterpret_cast<uint4*>(&sdt[r][s * 8]) = *reinterpret_cast<const uint4*>(dtb + g);
      *reinterpret_cast<uint4*>(&sx [r][s * 8]) = *reinterpret_cast<const uint4*>(xact + g);
    }
    {
      const int r = tid >> 2, s = tid & 3;
      *reinterpret_cast<uint4*>(&sbc[r][s * 8]) =
          *reinterpret_cast<const uint4*>(xdbl + (l0 + r) * 160 + 128 + s * 8);
    }
    __syncthreads();

    for (int l = 0; l < SCH; l++) {
      const float dtv = b2f(sdt[l][dd]);
      const float xv  = b2f(sx[l][dd]);
      const float u   = dtv * xv;
      ushort4 Bv = *reinterpret_cast<const ushort4*>(&sbc[l][nq * 4]);
      ushort4 Cv = *reinterpret_cast<const ushort4*>(&sbc[l][16 + nq * 4]);
      const ushort* Bp = (const ushort*)&Bv;
      const ushort* Cp = (const ushort*)&Cv;
      float p = 0.f;
#pragma unroll
      for (int n = 0; n < 4; n++) {
        const float dA = exp2f(dtv * a2[n]);
        st[n] = fmaf(st[n], dA, u * b2f(Bp[n]));
        q[n] *= dA;
        p = fmaf(st[n], b2f(Cp[n]), p);
      }
      p += __shfl_xor(p, 1);
      p += __shfl_xor(p, 2);
      if (nq == 0) sx[l][dd] = f2b(p + Dd * xv);   // same-wave: safe after reads
    }
    __syncthreads();
#pragma unroll
    for (int i = 0; i < 2; i++) {
      const int cc = tid + i * 256;
      const int r = cc >> 3, s = cc & 7;
      *reinterpret_cast<uint4*>(xact + (l0 + r) * 4096 + dblk + s * 8) =
          *reinterpret_cast<const uint4*>(&sx[r][s * 8]);
    }
    __syncthreads();
  }

  const size_t o = (((size_t)b * NC + c) * 4096 + d) * 16 + nq * 4;
  *reinterpret_cast<float4*>(Sout + o) = float4{st[0], st[1], st[2], st[3]};
  *reinterpret_cast<float4*>(Pout + o) = float4{q[0], q[1], q[2], q[3]};
}

// Phase B: chunk-boundary carry. SI[c] = state entering chunk c.
__global__ __launch_bounds__(256)
void scan_carry(const float* __restrict__ S, const float* __restrict__ P,
                float* __restrict__ SI)
{
  const int t  = blockIdx.x * 256 + threadIdx.x;   // [0, 2*65536)
  const int b  = t >> 16;
  const int dn = t & 65535;
  const size_t stride = (size_t)4096 * 16;
  const size_t o0 = (size_t)b * NC * stride + dn;
  float T = 0.f;
#pragma unroll
  for (int c = 0; c < NC; c++) {
    const size_t o = o0 + (size_t)c * stride;
    SI[o] = T;
    T = fmaf(P[o], T, S[o]);
  }
}

// Phase C: correction + gating. y = (partA + sum_n C*q)*silu(z), q seeded SI.
__global__ __launch_bounds__(256)
void scan_fix(const ushort* __restrict__ dtb,
              const ushort* __restrict__ partA,    // buf2
              ushort* __restrict__ zy,             // in: z, out: y (buf1)
              const ushort* __restrict__ xdbl,
              const float*  __restrict__ Alog,
              const float*  __restrict__ SI)
{
  __shared__ ushort sdt[SCH][64];
  __shared__ ushort sp [SCH][64];
  __shared__ ushort sz [SCH][64];
  __shared__ ushort sbc[SCH][32];

  const int tid  = threadIdx.x;
  const int dblk = blockIdx.x * 64;
  const int b    = blockIdx.y;
  const int c    = blockIdx.z;
  const int dd   = tid >> 2;
  const int nq   = tid & 3;
  const int d    = dblk + dd;

  float a2[4];
#pragma unroll
  for (int n = 0; n < 4; n++)
    a2[n] = -__expf(Alog[(size_t)d * 16 + nq * 4 + n]) * 1.44269504f;

  float q[4];
  {
    float4 s4 = *reinterpret_cast<const float4*>(
        SI + (((size_t)b * NC + c) * 4096 + d) * 16 + nq * 4);
    q[0] = s4.x; q[1] = s4.y; q[2] = s4.z; q[3] = s4.w;
  }

  const size_t rbase = (size_t)b * 2048 + (size_t)c * CLEN;
  for (int sub = 0; sub < CLEN / SCH; sub++) {
    const size_t l0 = rbase + sub * SCH;
#pragma unroll
    for (int i = 0; i < 2; i++) {
      const int cc = tid + i * 256;
      const int r = cc >> 3, s = cc & 7;
      const size_t g = (l0 + r) * 4096 + dblk + s * 8;
      *reinterpret_cast<uint4*>(&sdt[r][s * 8]) = *reinterpret_cast<const uint4*>(dtb + g);
      *reinterpret_cast<uint4*>(&sp [r][s * 8]) = *reinterpret_cast<const uint4*>(partA + g);
      *reinterpret_cast<uint4*>(&sz [r][s * 8]) = *reinterpret_cast<const uint4*>(zy + g);
    }
    {
      const int r = tid >> 2, s = tid & 3;
      *reinterpret_cast<uint4*>(&sbc[r][s * 8]) =
          *reinterpret_cast<const uint4*>(xdbl + (l0 + r) * 160 + 128 + s * 8);
    }
    __syncthreads();

    for (int l = 0; l < SCH; l++) {
      const float dtv = b2f(sdt[l][dd]);
      ushort4 Cv = *reinterpret_cast<const ushort4*>(&sbc[l][16 + nq * 4]);
      const ushort* Cp = (const ushort*)&Cv;
      float corr = 0.f;
#pragma unroll
      for (int n = 0; n < 4; n++) {
        q[n] *= exp2f(dtv * a2[n]);
        corr = fmaf(q[n], b2f(Cp[n]), corr);
      }
      corr += __shfl_xor(corr, 1);
      corr += __shfl_xor(corr, 2);
      if (nq == 0) {
        const float pa = b2f(sp[l][dd]);
        const float zv = b2f(sz[l][dd]);
        const float sig = 1.0f / (1.0f + __expf(-zv));
        sz[l][dd] = f2b((pa + corr) * (zv * sig));
      }
    }
    __syncthreads();
#pragma unroll
    for (int i = 0; i < 2; i++) {
      const int cc = tid + i * 256;
      const int r = cc >> 3, s = cc & 7;
      *reinterpret_cast<uint4*>(zy + (l0 + r) * 4096 + dblk + s * 8) =
          *reinterpret_cast<const uint4*>(&sz[r][s * 8]);
    }
    __syncthreads();
  }
}

// ---------------------------------------------------------------------------
extern "C" void kernel_launch(void* const* d_in, const int* in_sizes, int n_in,
                              void* d_out, int out_size, void* d_ws, size_t ws_size,
                              hipStream_t stream)
{
  const float* hid  = (const float*)d_in[0];
  const float* Win  = (const float*)d_in[1];
  const float* cw   = (const float*)d_in[2];
  const float* cb   = (const float*)d_in[3];
  const float* Wx   = (const float*)d_in[4];
  const float* Wdt  = (const float*)d_in[5];
  const float* bdt  = (const float*)d_in[6];
  const float* Alog = (const float*)d_in[7];
  const float* Dp   = (const float*)d_in[8];
  const float* Wout = (const float*)d_in[9];
  float* outp = (float*)d_out;

  char* ws = (char*)d_ws;
  const size_t SZ = (size_t)4096 * 4096 * sizeof(ushort);
  ushort* buf0 = (ushort*)(ws);            // x_raw, later dt
  ushort* buf1 = (ushort*)(ws + SZ);       // z, later y
  ushort* buf2 = (ushort*)(ws + 2 * SZ);   // x_act, later partA
  ushort* buf3 = (ushort*)(ws + 3 * SZ);   // x_dbl [4096][160]

  // d_out doubles as scratch until GEMM4 overwrites it:
  //   W   (fp32 [4096][160], split-K accum)  at offset 0   (dead after convert)
  //   S/P/SI (fp32 [2][NC][4096][16] each = 8.4MB)         (scan phases)
  float* Wacc = outp;
  float* Sarr = outp;                       // overlaps Wacc, temporally disjoint
  float* Parr = outp + (size_t)2 * NC * 4096 * 16;
  float* SIar = outp + (size_t)4 * NC * 4096 * 16;

  // 1) xz = hidden @ W_in^T -> x (buf0), z (buf1)
  gemm_kernel<0, true><<<dim3(8192 / BN, 4096 / BM), 256, 0, stream>>>(
      hid, 2048, Win, 2048, 4096, 8192, 2048, 2048, buf0, buf1, nullptr, 4096, nullptr);

  // 2) causal depthwise conv + SiLU -> x_act (buf2)
  conv_silu_kernel<<<(4096 * 512) / 256, 256, 0, stream>>>(buf0, cw, cb, buf2);

  // 3) x_dbl = x_act @ W_x^T, split-K=8 atomic fp32, then convert -> buf3
  hipMemsetAsync(Wacc, 0, (size_t)4096 * 160 * sizeof(float), stream);
  gemm_kernel<4, false><<<dim3(2, 4096 / BM, 8), 256, 0, stream>>>(
      buf2, 4096, Wx, 4096, 4096, 160, 4096, 512, nullptr, nullptr, Wacc, 160, nullptr);
  f32_to_bf16_kernel<<<(4096 * 160 / 4 + 255) / 256, 256, 0, stream>>>(
      Wacc, buf3, 4096 * 160 / 4);

  // 4) dt = softplus(dt_lr @ W_dt^T + b_dt) -> buf0
  gemm_kernel<2, false><<<dim3(4096 / BN, 4096 / BM), 256, 0, stream>>>(
      buf3, 160, Wdt, 128, 4096, 4096, 128, 128, buf0, nullptr, nullptr, 4096, bdt);

  // 5) chunked scan: A (partA over buf2, S/P), carry (SI), fix (y over buf1)
  scan_partA<<<dim3(64, 2, NC), 256, 0, stream>>>(buf0, buf2, buf3, Alog, Dp, Sarr, Parr);
  scan_carry<<<(2 * 65536) / 256, 256, 0, stream>>>(Sarr, Parr, SIar);
  scan_fix<<<dim3(64, 2, NC), 256, 0, stream>>>(buf0, buf2, buf1, buf3, Alog, SIar);

  // 6) out = y @ W_out^T -> fp32 d_out (overwrites all scratch in d_out)
  gemm_kernel<3, false><<<dim3(2048 / BN, 4096 / BM), 256, 0, stream>>>(
      buf1, 4096, Wout, 4096, 4096, 2048, 4096, 4096, nullptr, nullptr, outp, 2048, nullptr);
}

// Round 4
// 812.019 us; speedup vs baseline: 2.1870x; 1.4779x over previous
//
#include <hip/hip_runtime.h>

typedef __bf16 bf16x8 __attribute__((ext_vector_type(8)));
typedef float  f32x4  __attribute__((ext_vector_type(4)));

__device__ __forceinline__ float b2f(ushort u){
  return __builtin_bit_cast(float, ((uint)u) << 16);
}
__device__ __forceinline__ ushort f2b(float f){
  uint i = __builtin_bit_cast(uint, f);
  uint r = i + 0x7FFFu + ((i >> 16) & 1u);
  return (ushort)(r >> 16);
}
__device__ __forceinline__ uint4 cvt8(const float* __restrict__ p){
  float4 a = *reinterpret_cast<const float4*>(p);
  float4 b = *reinterpret_cast<const float4*>(p + 4);
  uint4 r;
  r.x = (uint)f2b(a.x) | ((uint)f2b(a.y) << 16);
  r.y = (uint)f2b(a.z) | ((uint)f2b(a.w) << 16);
  r.z = (uint)f2b(b.x) | ((uint)f2b(b.y) << 16);
  r.w = (uint)f2b(b.z) | ((uint)f2b(b.w) << 16);
  return r;
}

// async global->LDS, 16B per lane, LDS dest = wave-uniform base + lane*16
__device__ __forceinline__ void gload16(const ushort* g, ushort* l){
  __builtin_amdgcn_global_load_lds(
      (__attribute__((address_space(1))) void*)g,
      (__attribute__((address_space(3))) void*)l, 16, 0, 0);
}

// ---------------------------------------------------------------------------
// fp32 -> bf16 bulk convert; t >= n8src writes zeros (pad rows)
// ---------------------------------------------------------------------------
__global__ __launch_bounds__(256)
void cvt_kernel(const float* __restrict__ in, ushort* __restrict__ out,
                int n8, int n8src)
{
  const int t = blockIdx.x * 256 + threadIdx.x;
  if (t >= n8) return;
  uint4 v = uint4{0u, 0u, 0u, 0u};
  if (t < n8src) v = cvt8(in + (size_t)t * 8);
  *reinterpret_cast<uint4*>(out + (size_t)t * 8) = v;
}

// ---------------------------------------------------------------------------
// m97-style MFMA GEMM: C[M][N] = A[M][K] * B[N][K]^T, both bf16.
// 128x128 tile, BK=32, global_load_lds width-16 staging, 4 waves (2x2),
// each wave 64x64 via 4x4 accs of 16x16x32 bf16 MFMA.
// kSlice = K-range per blockIdx.z (split-K); pass K for no split.
// EPI: 0 xz-split bf16, 1 bf16 N-guard, 2 softplus+bias bf16,
//      3 fp32 store, 4 fp32 atomicAdd (split-K)
// ---------------------------------------------------------------------------
#define BM 128
#define BN 128
#define BK 32

template<int EPI>
__global__ __launch_bounds__(256)
void gemm_kernel(const ushort* __restrict__ A, int lda,
                 const ushort* __restrict__ B, int ldb,
                 int M, int N, int kSlice,
                 ushort* __restrict__ out0, ushort* __restrict__ out1,
                 float* __restrict__ outF, int ldo,
                 const float* __restrict__ bias)
{
  __shared__ ushort As[BM * BK];
  __shared__ ushort Bs[BN * BK];

  const int tid   = threadIdx.x;
  const int wave  = tid >> 6;
  const int lane  = tid & 63;
  const int row16 = lane & 15;
  const int quad  = lane >> 4;
  const int wm    = (wave >> 1) * 64;
  const int wn    = (wave & 1) * 64;
  const int tileM = blockIdx.y * BM;
  const int tileN = blockIdx.x * BN;
  const int kBeg  = blockIdx.z * kSlice;

  const int srow = lane >> 2;          // 0..15 within 16-row chunk
  const int scol = (lane & 3) * 8;     // 0,8,16,24

  f32x4 acc[4][4];
#pragma unroll
  for (int i = 0; i < 4; i++)
#pragma unroll
    for (int j = 0; j < 4; j++)
      acc[i][j] = f32x4{0.f, 0.f, 0.f, 0.f};

  for (int k0 = kBeg; k0 < kBeg + kSlice; k0 += BK) {
    // stage A/B via async direct-to-LDS: 8 chunks of 16 rows each, 2/wave
#pragma unroll
    for (int i = 0; i < 2; i++) {
      const int chunk = wave * 2 + i;
      const int row   = chunk * 16 + srow;
      gload16(A + (size_t)(tileM + row) * lda + k0 + scol, &As[chunk * 512]);
      gload16(B + (size_t)(tileN + row) * ldb + k0 + scol, &Bs[chunk * 512]);
    }
    __syncthreads();

    bf16x8 af[4], bfr[4];
#pragma unroll
    for (int mi = 0; mi < 4; mi++)
      af[mi] = *reinterpret_cast<const bf16x8*>(&As[(wm + mi * 16 + row16) * BK + quad * 8]);
#pragma unroll
    for (int ni = 0; ni < 4; ni++)
      bfr[ni] = *reinterpret_cast<const bf16x8*>(&Bs[(wn + ni * 16 + row16) * BK + quad * 8]);

#pragma unroll
    for (int mi = 0; mi < 4; mi++)
#pragma unroll
      for (int ni = 0; ni < 4; ni++)
        acc[mi][ni] = __builtin_amdgcn_mfma_f32_16x16x32_bf16(af[mi], bfr[ni], acc[mi][ni], 0, 0, 0);
    __syncthreads();
  }

  // epilogue: C row = quad*4 + reg, col = lane&15
#pragma unroll
  for (int mi = 0; mi < 4; mi++) {
#pragma unroll
    for (int ni = 0; ni < 4; ni++) {
      const int nbase = tileN + wn + ni * 16 + row16;
#pragma unroll
      for (int r = 0; r < 4; r++) {
        const int m = tileM + wm + mi * 16 + quad * 4 + r;
        float v = acc[mi][ni][r];
        if (EPI == 0) {
          const ushort hv = f2b(v);
          const size_t idx = (size_t)m * ldo + (nbase >> 1);
          if (nbase & 1) out1[idx] = hv; else out0[idx] = hv;
        } else if (EPI == 1) {
          if (nbase < N) out0[(size_t)m * ldo + nbase] = f2b(v);
        } else if (EPI == 2) {
          float t = v + bias[nbase];
          float sp = (t > 20.0f) ? t : __logf(1.0f + __expf(t));
          out0[(size_t)m * ldo + nbase] = f2b(sp);
        } else if (EPI == 3) {
          if (nbase < N) outF[(size_t)m * ldo + nbase] = v;
        } else {
          if (nbase < N) atomicAdd(&outF[(size_t)m * ldo + nbase], v);
        }
      }
    }
  }
}

// ---------------------------------------------------------------------------
// Depthwise causal conv (width 4) + bias + SiLU.  x (bf16 ws) in [b][l][d].
// ---------------------------------------------------------------------------
__global__ __launch_bounds__(256)
void conv_silu_kernel(const ushort* __restrict__ xraw, const float* __restrict__ cw,
                      const float* __restrict__ cb, ushort* __restrict__ xact)
{
  const int t  = blockIdx.x * 256 + threadIdx.x;
  const int m  = t >> 9;
  const int d0 = (t & 511) << 3;
  const int l  = m & 2047;

  float acc[8];
  {
    float4 c0 = *reinterpret_cast<const float4*>(cb + d0);
    float4 c1 = *reinterpret_cast<const float4*>(cb + d0 + 4);
    acc[0] = c0.x; acc[1] = c0.y; acc[2] = c0.z; acc[3] = c0.w;
    acc[4] = c1.x; acc[5] = c1.y; acc[6] = c1.z; acc[7] = c1.w;
  }
  float wf[8][4];
#pragma unroll
  for (int i = 0; i < 8; i++) {
    float4 w4 = *reinterpret_cast<const float4*>(cw + (size_t)(d0 + i) * 4);
    wf[i][0] = w4.x; wf[i][1] = w4.y; wf[i][2] = w4.z; wf[i][3] = w4.w;
  }
#pragma unroll
  for (int k = 0; k < 4; k++) {
    const int lsrc = l - 3 + k;
    if (lsrc >= 0) {
      uint4 xv = *reinterpret_cast<const uint4*>(xraw + (size_t)(m - 3 + k) * 4096 + d0);
      const ushort* xp = (const ushort*)&xv;
#pragma unroll
      for (int i = 0; i < 8; i++) acc[i] += b2f(xp[i]) * wf[i][k];
    }
  }
  uint4 ov;
  ushort* op = (ushort*)&ov;
#pragma unroll
  for (int i = 0; i < 8; i++) {
    float a = acc[i];
    float s = a / (1.0f + __expf(-a));
    op[i] = f2b(s);
  }
  *reinterpret_cast<uint4*>(xact + (size_t)m * 4096 + d0) = ov;
}

// ---------------------------------------------------------------------------
// Chunked parallel scan.  L=2048 -> NC=16 chunks of CLEN=128.
// ---------------------------------------------------------------------------
#define NC 16
#define CLEN 128
#define SCH 64

__global__ __launch_bounds__(256)
void scan_partA(const ushort* __restrict__ dtb,
                ushort* __restrict__ xact,          // in: x_act, out: partA
                const ushort* __restrict__ xdbl,
                const float*  __restrict__ Alog,
                const float*  __restrict__ Dp,
                float* __restrict__ Sout, float* __restrict__ Pout)
{
  __shared__ ushort sdt[SCH][64];
  __shared__ ushort sx [SCH][64];
  __shared__ ushort sbc[SCH][32];

  const int tid  = threadIdx.x;
  const int dblk = blockIdx.x * 64;
  const int b    = blockIdx.y;
  const int c    = blockIdx.z;
  const int dd   = tid >> 2;
  const int nq   = tid & 3;
  const int d    = dblk + dd;

  float a2[4];
#pragma unroll
  for (int n = 0; n < 4; n++)
    a2[n] = -__expf(Alog[(size_t)d * 16 + nq * 4 + n]) * 1.44269504f;
  const float Dd = Dp[d];

  float st[4] = {0.f, 0.f, 0.f, 0.f};
  float q [4] = {1.f, 1.f, 1.f, 1.f};

  const size_t rbase = (size_t)b * 2048 + (size_t)c * CLEN;
  for (int sub = 0; sub < CLEN / SCH; sub++) {
    const size_t l0 = rbase + sub * SCH;
#pragma unroll
    for (int i = 0; i < 2; i++) {
      const int cc = tid + i * 256;
      const int r = cc >> 3, s = cc & 7;
      const size_t g = (l0 + r) * 4096 + dblk + s * 8;
      *reinterpret_cast<uint4*>(&sdt[r][s * 8]) = *reinterpret_cast<const uint4*>(dtb + g);
      *reinterpret_cast<uint4*>(&sx [r][s * 8]) = *reinterpret_cast<const uint4*>(xact + g);
    }
    {
      const int r = tid >> 2, s = tid & 3;
      *reinterpret_cast<uint4*>(&sbc[r][s * 8]) =
          *reinterpret_cast<const uint4*>(xdbl + (l0 + r) * 160 + 128 + s * 8);
    }
    __syncthreads();

    for (int l = 0; l < SCH; l++) {
      const float dtv = b2f(sdt[l][dd]);
      const float xv  = b2f(sx[l][dd]);
      const float u   = dtv * xv;
      ushort4 Bv = *reinterpret_cast<const ushort4*>(&sbc[l][nq * 4]);
      ushort4 Cv = *reinterpret_cast<const ushort4*>(&sbc[l][16 + nq * 4]);
      const ushort* Bp = (const ushort*)&Bv;
      const ushort* Cp = (const ushort*)&Cv;
      float p = 0.f;
#pragma unroll
      for (int n = 0; n < 4; n++) {
        const float dA = exp2f(dtv * a2[n]);
        st[n] = fmaf(st[n], dA, u * b2f(Bp[n]));
        q[n] *= dA;
        p = fmaf(st[n], b2f(Cp[n]), p);
      }
      p += __shfl_xor(p, 1);
      p += __shfl_xor(p, 2);
      if (nq == 0) sx[l][dd] = f2b(p + Dd * xv);
    }
    __syncthreads();
#pragma unroll
    for (int i = 0; i < 2; i++) {
      const int cc = tid + i * 256;
      const int r = cc >> 3, s = cc & 7;
      *reinterpret_cast<uint4*>(xact + (l0 + r) * 4096 + dblk + s * 8) =
          *reinterpret_cast<const uint4*>(&sx[r][s * 8]);
    }
    __syncthreads();
  }

  const size_t o = (((size_t)b * NC + c) * 4096 + d) * 16 + nq * 4;
  *reinterpret_cast<float4*>(Sout + o) = float4{st[0], st[1], st[2], st[3]};
  *reinterpret_cast<float4*>(Pout + o) = float4{q[0], q[1], q[2], q[3]};
}

__global__ __launch_bounds__(256)
void scan_carry(const float* __restrict__ S, const float* __restrict__ P,
                float* __restrict__ SI)
{
  const int t  = blockIdx.x * 256 + threadIdx.x;
  const int b  = t >> 16;
  const int dn = t & 65535;
  const size_t stride = (size_t)4096 * 16;
  const size_t o0 = (size_t)b * NC * stride + dn;
  float T = 0.f;
#pragma unroll
  for (int c = 0; c < NC; c++) {
    const size_t o = o0 + (size_t)c * stride;
    SI[o] = T;
    T = fmaf(P[o], T, S[o]);
  }
}

__global__ __launch_bounds__(256)
void scan_fix(const ushort* __restrict__ dtb,
              const ushort* __restrict__ partA,
              ushort* __restrict__ zy,             // in: z, out: y
              const ushort* __restrict__ xdbl,
              const float*  __restrict__ Alog,
              const float*  __restrict__ SI)
{
  __shared__ ushort sdt[SCH][64];
  __shared__ ushort sp [SCH][64];
  __shared__ ushort sz [SCH][64];
  __shared__ ushort sbc[SCH][32];

  const int tid  = threadIdx.x;
  const int dblk = blockIdx.x * 64;
  const int b    = blockIdx.y;
  const int c    = blockIdx.z;
  const int dd   = tid >> 2;
  const int nq   = tid & 3;
  const int d    = dblk + dd;

  float a2[4];
#pragma unroll
  for (int n = 0; n < 4; n++)
    a2[n] = -__expf(Alog[(size_t)d * 16 + nq * 4 + n]) * 1.44269504f;

  float q[4];
  {
    float4 s4 = *reinterpret_cast<const float4*>(
        SI + (((size_t)b * NC + c) * 4096 + d) * 16 + nq * 4);
    q[0] = s4.x; q[1] = s4.y; q[2] = s4.z; q[3] = s4.w;
  }

  const size_t rbase = (size_t)b * 2048 + (size_t)c * CLEN;
  for (int sub = 0; sub < CLEN / SCH; sub++) {
    const size_t l0 = rbase + sub * SCH;
#pragma unroll
    for (int i = 0; i < 2; i++) {
      const int cc = tid + i * 256;
      const int r = cc >> 3, s = cc & 7;
      const size_t g = (l0 + r) * 4096 + dblk + s * 8;
      *reinterpret_cast<uint4*>(&sdt[r][s * 8]) = *reinterpret_cast<const uint4*>(dtb + g);
      *reinterpret_cast<uint4*>(&sp [r][s * 8]) = *reinterpret_cast<const uint4*>(partA + g);
      *reinterpret_cast<uint4*>(&sz [r][s * 8]) = *reinterpret_cast<const uint4*>(zy + g);
    }
    {
      const int r = tid >> 2, s = tid & 3;
      *reinterpret_cast<uint4*>(&sbc[r][s * 8]) =
          *reinterpret_cast<const uint4*>(xdbl + (l0 + r) * 160 + 128 + s * 8);
    }
    __syncthreads();

    for (int l = 0; l < SCH; l++) {
      const float dtv = b2f(sdt[l][dd]);
      ushort4 Cv = *reinterpret_cast<const ushort4*>(&sbc[l][16 + nq * 4]);
      const ushort* Cp = (const ushort*)&Cv;
      float corr = 0.f;
#pragma unroll
      for (int n = 0; n < 4; n++) {
        q[n] *= exp2f(dtv * a2[n]);
        corr = fmaf(q[n], b2f(Cp[n]), corr);
      }
      corr += __shfl_xor(corr, 1);
      corr += __shfl_xor(corr, 2);
      if (nq == 0) {
        const float pa = b2f(sp[l][dd]);
        const float zv = b2f(sz[l][dd]);
        const float sig = 1.0f / (1.0f + __expf(-zv));
        sz[l][dd] = f2b((pa + corr) * (zv * sig));
      }
    }
    __syncthreads();
#pragma unroll
    for (int i = 0; i < 2; i++) {
      const int cc = tid + i * 256;
      const int r = cc >> 3, s = cc & 7;
      *reinterpret_cast<uint4*>(zy + (l0 + r) * 4096 + dblk + s * 8) =
          *reinterpret_cast<const uint4*>(&sz[r][s * 8]);
    }
    __syncthreads();
  }
}

// ---------------------------------------------------------------------------
extern "C" void kernel_launch(void* const* d_in, const int* in_sizes, int n_in,
                              void* d_out, int out_size, void* d_ws, size_t ws_size,
                              hipStream_t stream)
{
  const float* hid  = (const float*)d_in[0];
  const float* Win  = (const float*)d_in[1];
  const float* cw   = (const float*)d_in[2];
  const float* cb   = (const float*)d_in[3];
  const float* Wx   = (const float*)d_in[4];
  const float* Wdt  = (const float*)d_in[5];
  const float* bdt  = (const float*)d_in[6];
  const float* Alog = (const float*)d_in[7];
  const float* Dp   = (const float*)d_in[8];
  const float* Wout = (const float*)d_in[9];
  float* outp = (float*)d_out;

  char* ws = (char*)d_ws;
  const size_t SZ = (size_t)4096 * 4096 * sizeof(ushort);   // 33.55 MB
  ushort* buf0 = (ushort*)(ws);                 // x_raw -> dt
  ushort* buf1 = (ushort*)(ws + SZ);            // z -> y
  ushort* buf2 = (ushort*)(ws + 2 * SZ);        // hid_bf16 -> x_act/partA -> Wout_bf16
  ushort* buf3 = (ushort*)(ws + 3 * SZ);        // x_dbl [4096][160]
  ushort* wxb  = (ushort*)(ws + 3 * SZ + (2u << 20));   // Wx bf16 [256][4096] (pad)
  ushort* wdtb = (ushort*)(ws + 3 * SZ + (4u << 20));   // Wdt bf16 [4096][128]

  // d_out as temporal scratch: Win_bf16 (whole), later Wacc / S / P / SI
  ushort* winb = (ushort*)outp;                 // 16.77M bf16 = 33.55 MB exactly
  float* Wacc = outp;
  float* Sarr = outp;
  float* Parr = outp + (size_t)2 * NC * 4096 * 16;
  float* SIar = outp + (size_t)4 * NC * 4096 * 16;

  // 0) bulk fp32->bf16 converts
  cvt_kernel<<<1048576 / 256, 256, 0, stream>>>(hid, buf2, 1048576, 1048576);
  cvt_kernel<<<2097152 / 256, 256, 0, stream>>>(Win, winb, 2097152, 2097152);

  // 1) xz = hidden @ W_in^T -> x (buf0), z (buf1)
  gemm_kernel<0><<<dim3(8192 / BN, 4096 / BM), 256, 0, stream>>>(
      buf2, 2048, winb, 2048, 4096, 8192, 2048, buf0, buf1, nullptr, 4096, nullptr);

  // 2) causal depthwise conv + SiLU -> x_act (buf2; hid_bf16 dead)
  conv_silu_kernel<<<(4096 * 512) / 256, 256, 0, stream>>>(buf0, cw, cb, buf2);

  // 3) x_dbl = x_act @ W_x^T, split-K=8 atomic fp32 -> convert -> buf3
  cvt_kernel<<<131072 / 256, 256, 0, stream>>>(Wx, wxb, 131072, 81920);
  cvt_kernel<<<65536 / 256, 256, 0, stream>>>(Wdt, wdtb, 65536, 65536);
  hipMemsetAsync(Wacc, 0, (size_t)4096 * 160 * sizeof(float), stream);
  gemm_kernel<4><<<dim3(2, 4096 / BM, 8), 256, 0, stream>>>(
      buf2, 4096, wxb, 4096, 4096, 160, 512, nullptr, nullptr, Wacc, 160, nullptr);
  cvt_kernel<<<81920 / 256, 256, 0, stream>>>(Wacc, buf3, 81920, 81920);

  // 4) dt = softplus(dt_lr @ W_dt^T + b_dt) -> buf0
  gemm_kernel<2><<<dim3(4096 / BN, 4096 / BM), 256, 0, stream>>>(
      buf3, 160, wdtb, 128, 4096, 4096, 128, buf0, nullptr, nullptr, 4096, bdt);

  // 5) chunked scan
  scan_partA<<<dim3(64, 2, NC), 256, 0, stream>>>(buf0, buf2, buf3, Alog, Dp, Sarr, Parr);
  scan_carry<<<(2 * 65536) / 256, 256, 0, stream>>>(Sarr, Parr, SIar);
  scan_fix<<<dim3(64, 2, NC), 256, 0, stream>>>(buf0, buf2, buf1, buf3, Alog, SIar);

  // 6) out = y @ W_out^T -> fp32 d_out (Wout_bf16 staged in buf2, now dead)
  cvt_kernel<<<1048576 / 256, 256, 0, stream>>>(Wout, buf2, 1048576, 1048576);
  gemm_kernel<3><<<dim3(2048 / BN, 4096 / BM), 256, 0, stream>>>(
      buf1, 4096, buf2, 4096, 4096, 2048, 4096, nullptr, nullptr, outp, 2048, nullptr);
}